// Round 1
// baseline (186.790 us; speedup 1.0000x reference)
//
#include <hip/hip_runtime.h>
#include <stdint.h>

#define BB    2048
#define DIN   4096
#define DOUT  4096

// ---------------------------------------------------------------------------
// i8 MFMA bit-GEMM. x,m -> ±1 int8; dot± = 2*sums - 4096;
// out = sums > thr  <=>  dot± > 2*thr - 4096. Exact in i32. (R7: absmax 0)
// ws: x8 ±1 [BB][DIN] @0 (8 MB); m8T ±1 [DOUT][DIN] @8MB (16 MB).
//
// R8 post-mortem: 48.4us, MfmaUtil 27.8% -> still barrier-drain-bound: the
// __syncthreads() per BK=128 chunk compiles to s_waitcnt vmcnt(0), draining
// the chunk+1 loads issued only ~1 chunk (~600-1100cyc) earlier vs ~900cyc
// HBM latency. Prefetch depth 1 + full drain = structurally exposed latency.
// R9 (T3+T4+T5): BK=64 half-chunks, 4 LDS buffers (same 64KB), prefetch
// depth 3, raw s_barrier + counted s_waitcnt vmcnt(12) (8/4/0 only in the
// 3 tail iterations), s_setprio(1) around the MFMA cluster. Swizzle
// re-derived for 64B rows: slot = kg ^ ((row>>1)&3) -> 4-way quad floor.
// ---------------------------------------------------------------------------

using v4i  = __attribute__((ext_vector_type(4)))  int;
using v16i = __attribute__((ext_vector_type(16))) int;

__device__ __forceinline__ void async_load16(const void* g, void* l) {
    __builtin_amdgcn_global_load_lds(
        (const __attribute__((address_space(1))) unsigned int*)g,
        (__attribute__((address_space(3))) unsigned int*)l,
        16, 0, 0);
}

// bytes {0,1} -> {+1, -1(0xFF)}; no cross-byte carries.
__device__ __forceinline__ unsigned int to_pm1(unsigned int c) {
    return c + ((c ^ 0x01010101u) * 255u);
}

// Fused packing (verified R7).
// blocks [0,BB): x int32 {0,1} row -> x8 ±1 bytes (same layout).
// blocks [BB, BB+4096): 64x64 transpose tile of masks -> m8T ±1 bytes.
__global__ void pack_all(const int* __restrict__ x,
                         const void* __restrict__ mraw,
                         char* __restrict__ x8,
                         char* __restrict__ m8T) {
    const int tid = threadIdx.x;
    if (blockIdx.x < BB) {
        const int row = blockIdx.x;
        const int4* src = (const int4*)(x + (size_t)row * DIN);
        unsigned int* dst = (unsigned int*)(x8 + (size_t)row * DIN);
        #pragma unroll
        for (int q = 0; q < 4; ++q) {
            int4 v = src[q * 256 + tid];           // coalesced 16B/lane
            unsigned int t = (unsigned int)(v.x & 1) |
                             ((unsigned int)(v.y & 1) << 8) |
                             ((unsigned int)(v.z & 1) << 16) |
                             ((unsigned int)(v.w & 1) << 24);
            dst[q * 256 + tid] = to_pm1(t);        // coalesced 4B/lane
        }
    } else {
        const int bw = blockIdx.x - BB;            // 0..4095
        const int k0 = (bw & 63) * 64;
        const int n0 = (bw >> 6) * 64;

        // inline dtype detect (u8-bool vs int32): wave-reduce 1 KB prefix.
        const unsigned char* mb = (const unsigned char*)mraw;
        int myv = (mb[tid] != 0) + (mb[tid + 256] != 0) +
                  (mb[tid + 512] != 0) + (mb[tid + 768] != 0);
        #pragma unroll
        for (int d = 32; d; d >>= 1) myv += __shfl_xor(myv, d);
        const bool isU8 = (myv > 64);   // u8 ~128/wave, int32 ~32/wave

        // 4x4 byte micro-tile per thread: rows k0+k4..+3, cols n0+n4..+3
        const int n4 = (tid & 15) * 4;
        const int k4 = (tid >> 4) * 4;
        unsigned int a[4];
        if (isU8) {
            #pragma unroll
            for (int r = 0; r < 4; ++r)
                a[r] = *(const unsigned int*)(mb + (size_t)(k0 + k4 + r) * DOUT + n0 + n4);
        } else {
            const int4* m32 = (const int4*)mraw;
            #pragma unroll
            for (int r = 0; r < 4; ++r) {
                int4 v = m32[((size_t)(k0 + k4 + r) * DOUT + n0 + n4) >> 2];
                a[r] = (unsigned int)(v.x & 1) |
                       ((unsigned int)(v.y & 1) << 8) |
                       ((unsigned int)(v.z & 1) << 16) |
                       ((unsigned int)(v.w & 1) << 24);
            }
        }
        // 4x4 byte transpose via v_perm (sel 0-3 = src1/lo, 4-7 = src0/hi)
        unsigned int x0 = __builtin_amdgcn_perm(a[1], a[0], 0x05010400u);
        unsigned int x1 = __builtin_amdgcn_perm(a[3], a[2], 0x05010400u);
        unsigned int x2 = __builtin_amdgcn_perm(a[1], a[0], 0x07030602u);
        unsigned int x3 = __builtin_amdgcn_perm(a[3], a[2], 0x07030602u);
        unsigned int c0 = __builtin_amdgcn_perm(x1, x0, 0x05040100u);
        unsigned int c1 = __builtin_amdgcn_perm(x1, x0, 0x07060302u);
        unsigned int c2 = __builtin_amdgcn_perm(x3, x2, 0x05040100u);
        unsigned int c3 = __builtin_amdgcn_perm(x3, x2, 0x07060302u);
        *(unsigned int*)(m8T + (size_t)(n0 + n4 + 0) * DIN + k0 + k4) = to_pm1(c0);
        *(unsigned int*)(m8T + (size_t)(n0 + n4 + 1) * DIN + k0 + k4) = to_pm1(c1);
        *(unsigned int*)(m8T + (size_t)(n0 + n4 + 2) * DIN + k0 + k4) = to_pm1(c2);
        *(unsigned int*)(m8T + (size_t)(n0 + n4 + 3) * DIN + k0 + k4) = to_pm1(c3);
    }
}

// i8 MFMA GEMM: 128(m)x128(n) block tile, 4 waves as 2x2 of 64x64 wave
// tiles (2x2 of v_mfma_i32_32x32x32_i8 each). BK=64 half-chunks, 64 steps,
// 4-buffer LDS (64 KB), prefetch depth 3, counted vmcnt (T3+T4), setprio
// around MFMA (T5).
// LDS layout: [row][slot], slot = kgroup ^ ((row>>1)&3), 4 kgroups x 16 B.
__global__ __launch_bounds__(256)
void bgemm(const char* __restrict__ x8,
           const char* __restrict__ m8T,
           const int* __restrict__ thr,
           int* __restrict__ out) {
    // XCD-aware swizzle: flat%8 = XCD (round-robin heuristic); each XCD gets
    // a compact 8m x 8n patch -> per-XCD L2 set ~8 MB instead of ~16.
    const int flat = blockIdx.y * 32 + blockIdx.x;
    const int xcd  = flat & 7;
    const int idx  = flat >> 3;                    // 0..63
    const int bm   = (xcd & 1) * 8 + (idx & 7);    // 0..15
    const int bn   = (xcd >> 1) * 8 + (idx >> 3);  // 0..31
    const int b0   = bm * 128;                     // m
    const int o0   = bn * 128;                     // n

    const int tid  = threadIdx.x;
    const int lane = tid & 63;
    const int wv   = tid >> 6;
    const int wm   = (wv & 1) * 64;      // wave tile m origin
    const int wn   = (wv >> 1) * 64;     // wave tile n origin
    const int l31  = lane & 31;
    const int lh   = lane >> 5;
    const int rsw2 = (l31 >> 1) & 3;     // (row>>1)&3 term for frag reads

    __shared__ __align__(16) char lA[4][128 * 64];
    __shared__ __align__(16) char lB[4][128 * 64];

    // stage step c -> buf. Per instr: 16 rows x 64 B contiguous LDS (1KB).
    // lane: row = r0 + l/4, slot s = l&3, global kgroup g = s ^ ((row>>1)&3).
    auto stage = [&](int c, int buf) {
        const int k0 = c * 64;
        const int ri = lane >> 2;            // 0..15
        const int s  = lane & 3;
        #pragma unroll
        for (int h = 0; h < 2; ++h) {
            const int r0  = wv * 32 + h * 16;
            const int row = r0 + ri;
            const int g   = s ^ ((row >> 1) & 3);
            async_load16(x8 + (size_t)(b0 + row) * DIN + k0 + g * 16,
                         &lA[buf][r0 * 64 + lane * 16]);
            async_load16(m8T + (size_t)(o0 + row) * DIN + k0 + g * 16,
                         &lB[buf][r0 * 64 + lane * 16]);
        }
    };

    v16i acc[2][2];
    #pragma unroll
    for (int t = 0; t < 2; ++t)
        #pragma unroll
        for (int u = 0; u < 2; ++u)
            acc[t][u] = (v16i)(0);

    // compute one BK=64 step out of buf: 2 ks x 4 MFMA.
    auto compute = [&](int buf) {
        __builtin_amdgcn_s_setprio(1);
        #pragma unroll
        for (int ks = 0; ks < 2; ++ks) {
            // slot of global kgroup (ks*2+lh) for this lane's rows
            const int slot = ((ks * 2 + lh) ^ rsw2) * 16;
            v4i aF[2], bF[2];
            #pragma unroll
            for (int t = 0; t < 2; ++t) {
                aF[t] = *(const v4i*)&lA[buf][(wm + t * 32 + l31) * 64 + slot];
                bF[t] = *(const v4i*)&lB[buf][(wn + t * 32 + l31) * 64 + slot];
            }
            acc[0][0] = __builtin_amdgcn_mfma_i32_32x32x32_i8(aF[0], bF[0], acc[0][0], 0, 0, 0);
            acc[0][1] = __builtin_amdgcn_mfma_i32_32x32x32_i8(aF[0], bF[1], acc[0][1], 0, 0, 0);
            acc[1][0] = __builtin_amdgcn_mfma_i32_32x32x32_i8(aF[1], bF[0], acc[1][0], 0, 0, 0);
            acc[1][1] = __builtin_amdgcn_mfma_i32_32x32x32_i8(aF[1], bF[1], acc[1][1], 0, 0, 0);
        }
        __builtin_amdgcn_s_setprio(0);
    };

    // prologue: 3 stages in flight (12 loads/thread).
    stage(0, 0);
    stage(1, 1);
    stage(2, 2);

    for (int s = 0; s < 64; ++s) {
        const int buf = s & 3;
        // issue prefetch for step s+3 into buf[(s+3)&3] = buf[(s-1)&3];
        // safe: end-of-step-(s-1) barrier already released that buffer.
        if (s < 61) {
            stage(s + 3, (s + 3) & 3);
            // 16 outstanding; drain only stage(s)'s 4, leave 12 in flight.
            asm volatile("s_waitcnt vmcnt(12)" ::: "memory");
        } else if (s == 61) {
            asm volatile("s_waitcnt vmcnt(8)" ::: "memory");
        } else if (s == 62) {
            asm volatile("s_waitcnt vmcnt(4)" ::: "memory");
        } else {
            asm volatile("s_waitcnt vmcnt(0)" ::: "memory");
        }
        __builtin_amdgcn_s_barrier();   // all waves' stage(s) landed
        compute(buf);
        __builtin_amdgcn_s_barrier();   // all waves done reading buf
    }

    // epilogue: out = (dot± > 2*thr - 4096).
    // C/D layout (verified R7): col = lane&31; row = (reg&3)+8*(reg>>2)+4*(lane>>5).
    #pragma unroll
    for (int u = 0; u < 2; ++u) {
        const int o   = o0 + wn + u * 32 + l31;
        const int lim = 2 * thr[o] - DIN;
        #pragma unroll
        for (int t = 0; t < 2; ++t) {
            #pragma unroll
            for (int r = 0; r < 16; ++r) {
                const int rowl = (r & 3) + 8 * (r >> 2) + 4 * lh;
                const int b    = b0 + wm + t * 32 + rowl;
                out[(size_t)b * DOUT + o] = (acc[t][u][r] > lim) ? 1 : 0;
            }
        }
    }
}

extern "C" void kernel_launch(void* const* d_in, const int* in_sizes, int n_in,
                              void* d_out, int out_size, void* d_ws, size_t ws_size,
                              hipStream_t stream) {
    const int* x          = (const int*)d_in[0];
    const void* masks     = d_in[1];           // bool: u8 or int32 (detected inline)
    const int* thresholds = (const int*)d_in[2];
    int* out              = (int*)d_out;

    char* x8  = (char*)d_ws;                          // 8 MB
    char* m8T = (char*)d_ws + ((size_t)8 << 20);      // 16 MB

    pack_all<<<BB + 4096, 256, 0, stream>>>(x, masks, x8, m8T);
    bgemm<<<dim3(32, 16), 256, 0, stream>>>(x8, m8T, thresholds, out);
}